// Round 5
// baseline (828.979 us; speedup 1.0000x reference)
//
#include <hip/hip_runtime.h>

#define VOX (128*128*32)   // 524288 voxels
#define CCH 64
#define NCL 20
#define DD 128
#define HH 128
#define WW 32
#define ZT 4
#define EPSV 1e-5f
#define THRESV 0.2f

// ---- order-preserving float <-> uint key for atomic min/max ----
__device__ __forceinline__ unsigned keyOf(float f){
    unsigned u = __float_as_uint(f);
    return (u & 0x80000000u) ? ~u : (u | 0x80000000u);
}
__device__ __forceinline__ float keyInv(unsigned k){
    unsigned u = (k & 0x80000000u) ? (k & 0x7fffffffu) : ~k;
    return __uint_as_float(u);
}

__global__ void k_init(unsigned* keys){
    int i = threadIdx.x;
    if (i < NCL){ keys[i] = 0xFFFFFFFFu; keys[NCL+i] = 0u; }
}

// ---- Pass A: logit (einsum + bias), softmax masks, per-voxel mean/max over C ----
__global__ __launch_bounds__(256) void k_logit_softmax(
    const float* __restrict__ x, const float* __restrict__ clsw,
    const float* __restrict__ clsb, float* __restrict__ masks,
    float* __restrict__ logit, float* __restrict__ mx, float* __restrict__ Mx)
{
    __shared__ float sw[NCL*CCH];
    __shared__ float sb[NCL];
    int tid = threadIdx.x;
    for (int q = tid; q < NCL*CCH; q += 256) sw[q] = clsw[q];
    if (tid < NCL) sb[tid] = clsb[tid];
    __syncthreads();
    int v = blockIdx.x*256 + tid;
    float acc[NCL];
    #pragma unroll
    for (int o=0;o<NCL;o++) acc[o] = sb[o];
    float s = 0.f, mm = -1e30f;
    for (int c=0;c<CCH;c++){
        float xv = x[c*VOX + v];
        s += xv; mm = fmaxf(mm, xv);
        #pragma unroll
        for (int o=0;o<NCL;o++) acc[o] = fmaf(xv, sw[o*CCH + c], acc[o]);
    }
    mx[v] = s * (1.f/64.f);
    Mx[v] = mm;
    float lm = acc[0];
    #pragma unroll
    for (int o=1;o<NCL;o++) lm = fmaxf(lm, acc[o]);
    float es = 0.f;
    #pragma unroll
    for (int o=0;o<NCL;o++){
        logit[o*VOX + v] = acc[o];
        float e = expf(acc[o] - lm);
        es += e; acc[o] = e;
    }
    float inv = 1.f/es;
    #pragma unroll
    for (int o=0;o<NCL;o++) masks[o*VOX + v] = acc[o]*inv;
}

// ---- Pass B: z-marching FIR conv, SGPR weights, write-late reg staging ----
// block = 128 threads: y = tid>>2 (32 rows), x0 = (tid&3)*8 (8 outputs in x).
// grid = (20 classes, 32 z-tiles, 4 y-tiles) = 2560 blocks; 8 blocks/CU (LDS-capped).
// Per phase: [barrier; regs->LDS; barrier; issue next slice loads; FMA body; finalize]
// so global latency hides under the ~16k-cycle FMA body (T14 write-late split).

#define F8(AL,AH,WV,q0,q1,q2,q3,q4,q5,q6,q7) { \
    AL.x=fmaf(q0,WV,AL.x); AL.y=fmaf(q1,WV,AL.y); AL.z=fmaf(q2,WV,AL.z); AL.w=fmaf(q3,WV,AL.w); \
    AH.x=fmaf(q4,WV,AH.x); AH.y=fmaf(q5,WV,AH.y); AH.z=fmaf(q6,WV,AH.z); AH.w=fmaf(q7,WV,AH.w); }

#define DZ8(AL,AH,WP) { \
    F8(AL,AH,(WP)[0], i0,i1,i2,i3,i4,i5,i6,i7) \
    F8(AL,AH,(WP)[1], i1,i2,i3,i4,i5,i6,i7,i8) \
    F8(AL,AH,(WP)[2], i2,i3,i4,i5,i6,i7,i8,i9) \
    F8(AL,AH,(WP)[3], i3,i4,i5,i6,i7,i8,i9,i10) \
    F8(AL,AH,(WP)[4], i4,i5,i6,i7,i8,i9,i10,i11) \
    F8(AL,AH,(WP)[5], i5,i6,i7,i8,i9,i10,i11,i12) \
    F8(AL,AH,(WP)[6], i6,i7,i8,i9,i10,i11,i12,i13) }

#define NSTG 14          // ceil(38*44 / 128)
#define SLICE (38*44)    // 1672

__global__ __launch_bounds__(128, 4) void k_conv5(const float* __restrict__ masksAll,
        const float* __restrict__ mxp, const float* __restrict__ Mxp,
        const float* __restrict__ cfr, float* __restrict__ G,
        unsigned* __restrict__ keys)
{
    __shared__ __align__(16) float FL[3][38][44];   // 20064 B
    __shared__ float r4[4];
    const int cls = blockIdx.x;
    const int z0 = blockIdx.y * ZT;
    const int y0 = blockIdx.z * 32;
    const int tid = threadIdx.x;
    const int y  = tid >> 2;          // 0..31
    const int x0 = (tid & 3) * 8;     // 0,8,16,24
    const float* mk = masksAll + (size_t)cls * VOX;
    const float* wcls = cfr + cls*1029;   // wave-uniform -> scalar loads

    float sm[NSTG], sa[NSTG], sb[NSTG];

    // issue loads of slice zi into stage regs
    auto issue = [&](int zi){
        const bool zok = (unsigned)zi < (unsigned)DD;
        #pragma unroll
        for (int it = 0; it < NSTG; ++it){
            int p = tid + it*128;
            int ly = p / 44;
            int lx = p - ly*44;
            int gy = y0 + ly - 3;
            int gx = lx - 3;
            bool ok = (p < SLICE) && zok &&
                      ((unsigned)gy < (unsigned)HH) && ((unsigned)gx < (unsigned)WW);
            float m = 0.f, aa = 0.f, bb = 0.f;
            if (ok){
                int idx = (zi*HH + gy)*WW + gx;
                m = mk[idx]; aa = mxp[idx]; bb = Mxp[idx];
            }
            sm[it] = m; sa[it] = aa; sb[it] = bb;
        }
    };

    float4 a0l{},a0h{},a1l{},a1h{},a2l{},a2h{},a3l{},a3h{},
           a4l{},a4h{},a5l{},a5h{},a6l{},a6h{};
    float hmn = 1e30f, hmx = -1e30f;

    issue(z0 - 3);   // prologue

    float* F0 = &FL[0][0][0];
    float* F1 = F0 + SLICE;
    float* F2 = F0 + 2*SLICE;

    for (int zi = z0 - 3; zi <= z0 + ZT + 2; ++zi){
        __syncthreads();          // previous compute done; LDS free
        #pragma unroll
        for (int it = 0; it < NSTG; ++it){
            int p = tid + it*128;
            if (p < SLICE){
                float m = sm[it];
                F0[p] = m * sa[it];
                F1[p] = m * sb[it];
                F2[p] = m;
            }
        }
        __syncthreads();          // slice ready
        if (zi < z0 + ZT + 2) issue(zi + 1);   // fire next loads (hidden under FMAs)

        const int lo = z0 + 3 - zi;                // okJ: J>=lo && J-lo<ZT (wave-uniform)
        const bool ok0 = (0>=lo) && (0-lo<ZT);
        const bool ok1 = (1>=lo) && (1-lo<ZT);
        const bool ok2 = (2>=lo) && (2-lo<ZT);
        const bool ok3 = (3>=lo) && (3-lo<ZT);
        const bool ok4 = (4>=lo) && (4-lo<ZT);
        const bool ok5 = (5>=lo) && (5-lo<ZT);
        const bool ok6 = (6>=lo) && (6-lo<ZT);

        #pragma unroll
        for (int t = 0; t < 3; ++t){
            const float* fb = &FL[t][y][x0];
            const float* wt = wcls + t*343;
            #pragma unroll 1
            for (int dy = 0; dy < 7; ++dy){
                const float* fr = fb + dy*44;
                const float4 A  = *(const float4*)(fr);
                const float4 B4 = *(const float4*)(fr + 4);
                const float4 C4 = *(const float4*)(fr + 8);
                const float4 D4 = *(const float4*)(fr + 12);
                const float i0=A.x,  i1=A.y,  i2=A.z,  i3=A.w;
                const float i4=B4.x, i5=B4.y, i6=B4.z, i7=B4.w;
                const float i8=C4.x, i9=C4.y, i10=C4.z, i11=C4.w;
                const float i12=D4.x, i13=D4.y;
                const float* wd = wt + dy*7;
                if (ok6) DZ8(a6l,a6h, wd + 0)      // dz = 0
                if (ok5) DZ8(a5l,a5h, wd + 49)     // dz = 1
                if (ok4) DZ8(a4l,a4h, wd + 98)     // dz = 2
                if (ok3) DZ8(a3l,a3h, wd + 147)    // dz = 3
                if (ok2) DZ8(a2l,a2h, wd + 196)    // dz = 4
                if (ok1) DZ8(a1l,a1h, wd + 245)    // dz = 5
                if (ok0) DZ8(a0l,a0h, wd + 294)    // dz = 6
            }
        }

        const int zo = zi - 3;
        if (zi >= z0 + 3){
            const int oidx = (zo*HH + (y0 + y))*WW + x0;
            const float4 mva = *(const float4*)(mk  + oidx);
            const float4 mvb = *(const float4*)(mk  + oidx + 4);
            const float4 mxa = *(const float4*)(mxp + oidx);
            const float4 mxb = *(const float4*)(mxp + oidx + 4);
            float4 r1, r2;
            r1.x = mva.x/(1.f + expf(-a0l.x));
            r1.y = mva.y/(1.f + expf(-a0l.y));
            r1.z = mva.z/(1.f + expf(-a0l.z));
            r1.w = mva.w/(1.f + expf(-a0l.w));
            r2.x = mvb.x/(1.f + expf(-a0h.x));
            r2.y = mvb.y/(1.f + expf(-a0h.y));
            r2.z = mvb.z/(1.f + expf(-a0h.z));
            r2.w = mvb.w/(1.f + expf(-a0h.w));
            *(float4*)(G + (size_t)cls*VOX + oidx)     = r1;
            *(float4*)(G + (size_t)cls*VOX + oidx + 4) = r2;
            float h0 = r1.x*mxa.x, h1 = r1.y*mxa.y, h2 = r1.z*mxa.z, h3 = r1.w*mxa.w;
            float h4 = r2.x*mxb.x, h5 = r2.y*mxb.y, h6 = r2.z*mxb.z, h7 = r2.w*mxb.w;
            hmn = fminf(hmn, fminf(fminf(fminf(h0,h1),fminf(h2,h3)), fminf(fminf(h4,h5),fminf(h6,h7))));
            hmx = fmaxf(hmx, fmaxf(fmaxf(fmaxf(h0,h1),fmaxf(h2,h3)), fmaxf(fmaxf(h4,h5),fmaxf(h6,h7))));
        }
        a0l=a1l; a0h=a1h; a1l=a2l; a1h=a2h; a2l=a3l; a2h=a3h;
        a3l=a4l; a3h=a4h; a4l=a5l; a4h=a5h; a5l=a6l; a5h=a6h;
        a6l = make_float4(0.f,0.f,0.f,0.f);
        a6h = make_float4(0.f,0.f,0.f,0.f);
    }

    #pragma unroll
    for (int off = 32; off > 0; off >>= 1){
        hmn = fminf(hmn, __shfl_xor(hmn, off));
        hmx = fmaxf(hmx, __shfl_xor(hmx, off));
    }
    if ((tid & 63) == 0){ r4[(tid>>6)*2] = hmn; r4[(tid>>6)*2+1] = hmx; }
    __syncthreads();
    if (tid == 0){
        atomicMin(&keys[cls],     keyOf(fminf(r4[0], r4[2])));
        atomicMax(&keys[NCL+cls], keyOf(fmaxf(r4[1], r4[3])));
    }
}

__global__ void k_thr(const unsigned* __restrict__ keys, float* __restrict__ hminA,
                      float* __restrict__ invR){
    int i = threadIdx.x;
    if (i < NCL){
        float hm = keyInv(keys[i]);
        float hM = keyInv(keys[NCL+i]);
        hminA[i] = hm;
        invR[i] = 1.f/(hM - hm);
    }
}

// ---- g = ma * (norm > 0.2), in place ----
__global__ __launch_bounds__(256) void k_region(float* G, const float* __restrict__ mx,
        const float* __restrict__ hminA, const float* __restrict__ invR)
{
    int i = blockIdx.y;
    int v = blockIdx.x*256 + threadIdx.x;
    float ma = G[i*VOX + v];
    float heat = ma * mx[v];
    float norm = (heat - hminA[i]) * invR[i];
    G[i*VOX + v] = (norm > THRESV) ? ma : 0.f;
}

// ---- per-(class,channel) sums S1 = sum x*g, S2 = sum (x*g)^2 ----
__global__ __launch_bounds__(256) void k_stats(const float* __restrict__ x,
        const float* G, float* __restrict__ part)
{
    int tid = threadIdx.x;
    int c = tid & 63, vg = tid >> 6;
    int v0 = blockIdx.x * 2048;
    float s1[NCL], s2[NCL];
    #pragma unroll
    for (int i=0;i<NCL;i++){ s1[i]=0.f; s2[i]=0.f; }
    const float* xc = x + c*VOX;
    for (int k=0;k<512;k++){
        int v = v0 + (k<<2) + vg;
        float xv = xc[v];
        #pragma unroll
        for (int i=0;i<NCL;i++){
            float p = xv * G[i*VOX + v];
            s1[i] += p;
            s2[i] = fmaf(p, p, s2[i]);
        }
    }
    __shared__ float red[4][64][2*NCL];
    #pragma unroll
    for (int i=0;i<NCL;i++){ red[vg][c][i] = s1[i]; red[vg][c][NCL+i] = s2[i]; }
    __syncthreads();
    if (vg == 0){
        float* dst = part + (size_t)blockIdx.x * (NCL*CCH*2);
        for (int i=0;i<NCL;i++){
            float a = red[0][c][i]+red[1][c][i]+red[2][c][i]+red[3][c][i];
            float b = red[0][c][NCL+i]+red[1][c][NCL+i]+red[2][c][NCL+i]+red[3][c][NCL+i];
            dst[i*CCH*2 + c*2 + 0] = a;
            dst[i*CCH*2 + c*2 + 1] = b;
        }
    }
}

// ---- finish stats: a = gamma*rinv, kc = beta - m*rinv*gamma ----
__global__ void k_params(const float* __restrict__ part, const float* __restrict__ gamma,
        const float* __restrict__ beta, float* __restrict__ aArr, float* __restrict__ kcArr)
{
    int i = blockIdx.x, c = threadIdx.x;
    float s1 = 0.f, s2 = 0.f;
    for (int b=0;b<256;b++){
        const float* p = part + (size_t)b*(NCL*CCH*2) + i*CCH*2 + c*2;
        s1 += p[0]; s2 += p[1];
    }
    float m   = s1 * (1.f/(float)VOX);
    float var = s2 * (1.f/(float)VOX) - m*m;
    float rinv = 1.f/sqrtf(var + EPSV);
    float gm = gamma[c];
    aArr[i*CCH + c]  = gm*rinv;
    kcArr[i*CCH + c] = beta[c] - m*rinv*gm;
}

__global__ void k_kcol(const float* __restrict__ kcArr, float* __restrict__ KcA){
    int c = threadIdx.x;
    if (c < CCH){
        float s = 0.f;
        for (int i=0;i<NCL;i++) s += kcArr[i*CCH + c];
        KcA[c] = s;
    }
}

// ---- final: out[c,v] = relu( x*Sum_i g_i*a_ic + K[c] ), in-place over d_out ----
__global__ __launch_bounds__(256) void k_final(const float* __restrict__ x,
        float* outAll, const float* __restrict__ aArr, const float* __restrict__ KcA)
{
    __shared__ float aL[NCL*CCH];
    __shared__ float KL[CCH];
    int tid = threadIdx.x;
    for (int q=tid; q<NCL*CCH; q+=256) aL[q] = aArr[q];
    if (tid < CCH) KL[tid] = KcA[tid];
    __syncthreads();
    int v = blockIdx.x*256 + tid;
    const float* Gp = outAll + (size_t)NCL*VOX;
    float g[NCL];
    #pragma unroll
    for (int i=0;i<NCL;i++) g[i] = Gp[i*VOX + v];
    #pragma unroll 4
    for (int c=0;c<CCH;c++){
        float P = 0.f;
        #pragma unroll
        for (int i=0;i<NCL;i++) P = fmaf(g[i], aL[i*CCH + c], P);
        float xv = x[c*VOX + v];
        outAll[c*VOX + v] = fmaxf(0.f, fmaf(xv, P, KL[c]));
    }
}

extern "C" void kernel_launch(void* const* d_in, const int* in_sizes, int n_in,
                              void* d_out, int out_size, void* d_ws, size_t ws_size,
                              hipStream_t stream)
{
    const float* x     = (const float*)d_in[0];
    const float* clsw  = (const float*)d_in[1];
    const float* clsb  = (const float*)d_in[2];
    const float* cfr   = (const float*)d_in[3];
    const float* gamma = (const float*)d_in[4];
    const float* beta  = (const float*)d_in[5];

    float* out   = (float*)d_out;
    float* logit = out + (size_t)CCH*VOX;     // second output
    float* masks = out;                       // scratch: out[0 .. 20V)
    float* G     = out + (size_t)NCL*VOX;     // scratch: out[20V .. 40V)

    float* ws    = (float*)d_ws;
    float* mxp   = ws;                        // V
    float* Mxp   = ws + VOX;                  // V
    unsigned* keys = (unsigned*)(ws + 2*(size_t)VOX);   // 40
    float* hminA = ws + 2*(size_t)VOX + 64;   // 20
    float* invR  = hminA + NCL;               // 20
    float* part  = ws + 2*(size_t)VOX + 128;  // 256*2560
    float* aArr  = part + 256*(NCL*CCH*2);    // 1280
    float* kcArr = aArr + NCL*CCH;            // 1280
    float* KcA   = kcArr + NCL*CCH;           // 64

    k_init<<<1, 64, 0, stream>>>(keys);
    k_logit_softmax<<<VOX/256, 256, 0, stream>>>(x, clsw, clsb, masks, logit, mxp, Mxp);
    k_conv5<<<dim3(NCL, 32, 4), 128, 0, stream>>>(masks, mxp, Mxp, cfr, G, keys);
    k_thr<<<1, 32, 0, stream>>>(keys, hminA, invR);
    k_region<<<dim3(VOX/256, NCL), 256, 0, stream>>>(G, mxp, hminA, invR);
    k_stats<<<256, 256, 0, stream>>>(x, G, part);
    k_params<<<NCL, CCH, 0, stream>>>(part, gamma, beta, aArr, kcArr);
    k_kcol<<<1, CCH, 0, stream>>>(kcArr, KcA);
    k_final<<<VOX/256, 256, 0, stream>>>(x, out, aArr, KcA);
}